// Round 1
// baseline (3995.999 us; speedup 1.0000x reference)
//
#include <hip/hip_runtime.h>
#include <math.h>

#define N_EMBD 768
#define N_HEAD 12
#define HEAD_DIM 64
#define SEQ 2048
#define BATCH 2
#define M_ROWS (BATCH * SEQ)  // 4096

// ---------------------------------------------------------------------------
// Kernel 1: QKV projection.  x[4096,768] @ W[768,2304] + b -> q,k,v each
// stored [B,H,T,D] so the attention kernel reads contiguously per (b,h).
// 64x64 output tile per block, 256 threads, each thread 4x4 outputs, K-tile 16.
// ---------------------------------------------------------------------------
__global__ __launch_bounds__(256) void qkv_gemm_kernel(
    const float* __restrict__ x,     // [4096, 768]
    const float* __restrict__ W,     // [768, 2304]
    const float* __restrict__ bias,  // [2304]
    float* __restrict__ qkv)         // q|k|v each BATCH*N_HEAD*SEQ*HEAD_DIM
{
    const int K = N_EMBD;        // 768
    const int N = 3 * N_EMBD;    // 2304
    __shared__ float xs[16][65]; // [kk][m], +1 pad
    __shared__ float ws[16][68]; // [kk][n], pad

    const int bm = blockIdx.y * 64;
    const int bn = blockIdx.x * 64;
    const int tid = threadIdx.x;
    const int tx = tid & 15;
    const int ty = tid >> 4;

    float acc[4][4];
#pragma unroll
    for (int i = 0; i < 4; i++)
#pragma unroll
        for (int j = 0; j < 4; j++) acc[i][j] = 0.f;

    for (int k0 = 0; k0 < K; k0 += 16) {
        // x tile: 64 rows x 16 k.  thread -> row tid/4, k-chunk (tid%4)*4
        {
            const int m = tid >> 2;
            const int kk = (tid & 3) << 2;
            const float4 xv = *(const float4*)(x + (size_t)(bm + m) * K + k0 + kk);
            xs[kk + 0][m] = xv.x;
            xs[kk + 1][m] = xv.y;
            xs[kk + 2][m] = xv.z;
            xs[kk + 3][m] = xv.w;
        }
        // W tile: 16 k x 64 n.  thread -> k tid/16, n-chunk (tid%16)*4 (coalesced)
        {
            const int kk = tid >> 4;
            const int n = (tid & 15) << 2;
            const float4 wv = *(const float4*)(W + (size_t)(k0 + kk) * N + bn + n);
            ws[kk][n + 0] = wv.x;
            ws[kk][n + 1] = wv.y;
            ws[kk][n + 2] = wv.z;
            ws[kk][n + 3] = wv.w;
        }
        __syncthreads();
#pragma unroll
        for (int kk = 0; kk < 16; kk++) {
            float a[4], b[4];
#pragma unroll
            for (int i = 0; i < 4; i++) a[i] = xs[kk][ty * 4 + i];
#pragma unroll
            for (int j = 0; j < 4; j++) b[j] = ws[kk][tx * 4 + j];
#pragma unroll
            for (int i = 0; i < 4; i++)
#pragma unroll
                for (int j = 0; j < 4; j++) acc[i][j] += a[i] * b[j];
        }
        __syncthreads();
    }

    // Epilogue: this block's 64 output columns lie entirely inside one of
    // {q,k,v} and one head (bn is a multiple of 64, N_EMBD = 12*64).
    const int which = bn / N_EMBD;           // 0=q 1=k 2=v
    const int rem = bn - which * N_EMBD;
    const int h = rem >> 6;
    float* dst = qkv + (size_t)which * (BATCH * N_HEAD * SEQ * HEAD_DIM);
#pragma unroll
    for (int i = 0; i < 4; i++) {
        const int m = bm + ty * 4 + i;
        const int b = m >> 11;       // / SEQ
        const int t = m & (SEQ - 1);
        const size_t base = (((size_t)(b * N_HEAD + h)) * SEQ + t) * HEAD_DIM;
#pragma unroll
        for (int j = 0; j < 4; j++) {
            const int d = tx * 4 + j;
            dst[base + d] = acc[i][j] + bias[bn + d];
        }
    }
}

// ---------------------------------------------------------------------------
// Kernel 2: causal flash attention, fp32.  One wave per (b,h,t) query row;
// lane = head-dim channel (D == 64 == wave size).  Online softmax, never
// materializes scores.
// ---------------------------------------------------------------------------
__global__ __launch_bounds__(256) void attn_kernel(
    const float* __restrict__ qkv,
    float* __restrict__ y)  // [B,T,C]
{
    const size_t QSZ = (size_t)BATCH * N_HEAD * SEQ * HEAD_DIM;
    const float* q = qkv;
    const float* k = qkv + QSZ;
    const float* v = qkv + 2 * QSZ;

    const int wave = (int)((blockIdx.x * blockDim.x + threadIdx.x) >> 6);
    const int lane = threadIdx.x & 63;
    const int t = wave & (SEQ - 1);
    const int bh = wave >> 11;  // b*N_HEAD + h

    const float* kb = k + (size_t)bh * SEQ * HEAD_DIM;
    const float* vb = v + (size_t)bh * SEQ * HEAD_DIM;

    const float scale = 0.125f;  // 1/sqrt(64)
    const float qv = q[(size_t)wave * HEAD_DIM + lane] * scale;

    float m = -INFINITY, l = 0.f, o = 0.f;
#pragma unroll 4
    for (int j = 0; j <= t; j++) {
        float s = qv * kb[(size_t)j * HEAD_DIM + lane];
        s += __shfl_xor(s, 32, 64);
        s += __shfl_xor(s, 16, 64);
        s += __shfl_xor(s, 8, 64);
        s += __shfl_xor(s, 4, 64);
        s += __shfl_xor(s, 2, 64);
        s += __shfl_xor(s, 1, 64);
        const float m_new = fmaxf(m, s);
        const float alpha = __expf(m - m_new);   // first iter: exp(-inf)=0
        const float p = __expf(s - m_new);
        l = l * alpha + p;
        o = o * alpha + p * vb[(size_t)j * HEAD_DIM + lane];
        m = m_new;
    }

    const int b = bh / N_HEAD;
    const int h = bh - b * N_HEAD;
    y[((size_t)(b * SEQ + t)) * N_EMBD + h * HEAD_DIM + lane] = o / l;
}

// ---------------------------------------------------------------------------
// Kernel 3: output projection.  y[4096,768] @ W_proj[768,768] + b -> out.
// Same tile structure as kernel 1, straight row-major write.
// ---------------------------------------------------------------------------
__global__ __launch_bounds__(256) void proj_gemm_kernel(
    const float* __restrict__ y,     // [4096, 768]
    const float* __restrict__ W,     // [768, 768]
    const float* __restrict__ bias,  // [768]
    float* __restrict__ out)         // [4096, 768]
{
    const int K = N_EMBD;
    const int N = N_EMBD;
    __shared__ float xs[16][65];
    __shared__ float ws[16][68];

    const int bm = blockIdx.y * 64;
    const int bn = blockIdx.x * 64;
    const int tid = threadIdx.x;
    const int tx = tid & 15;
    const int ty = tid >> 4;

    float acc[4][4];
#pragma unroll
    for (int i = 0; i < 4; i++)
#pragma unroll
        for (int j = 0; j < 4; j++) acc[i][j] = 0.f;

    for (int k0 = 0; k0 < K; k0 += 16) {
        {
            const int m = tid >> 2;
            const int kk = (tid & 3) << 2;
            const float4 xv = *(const float4*)(y + (size_t)(bm + m) * K + k0 + kk);
            xs[kk + 0][m] = xv.x;
            xs[kk + 1][m] = xv.y;
            xs[kk + 2][m] = xv.z;
            xs[kk + 3][m] = xv.w;
        }
        {
            const int kk = tid >> 4;
            const int n = (tid & 15) << 2;
            const float4 wv = *(const float4*)(W + (size_t)(k0 + kk) * N + bn + n);
            ws[kk][n + 0] = wv.x;
            ws[kk][n + 1] = wv.y;
            ws[kk][n + 2] = wv.z;
            ws[kk][n + 3] = wv.w;
        }
        __syncthreads();
#pragma unroll
        for (int kk = 0; kk < 16; kk++) {
            float a[4], b[4];
#pragma unroll
            for (int i = 0; i < 4; i++) a[i] = xs[kk][ty * 4 + i];
#pragma unroll
            for (int j = 0; j < 4; j++) b[j] = ws[kk][tx * 4 + j];
#pragma unroll
            for (int i = 0; i < 4; i++)
#pragma unroll
                for (int j = 0; j < 4; j++) acc[i][j] += a[i] * b[j];
        }
        __syncthreads();
    }

#pragma unroll
    for (int i = 0; i < 4; i++) {
        const int m = bm + ty * 4 + i;
#pragma unroll
        for (int j = 0; j < 4; j++) {
            const int n = bn + tx * 4 + j;
            out[(size_t)m * N + n] = acc[i][j] + bias[n];
        }
    }
}

// ---------------------------------------------------------------------------
extern "C" void kernel_launch(void* const* d_in, const int* in_sizes, int n_in,
                              void* d_out, int out_size, void* d_ws, size_t ws_size,
                              hipStream_t stream) {
    const float* x      = (const float*)d_in[0];
    const float* W_attn = (const float*)d_in[1];
    const float* b_attn = (const float*)d_in[2];
    const float* W_proj = (const float*)d_in[3];
    const float* b_proj = (const float*)d_in[4];
    float* out = (float*)d_out;

    const size_t QSZ = (size_t)BATCH * N_HEAD * SEQ * HEAD_DIM;  // 3,145,728
    float* qkv = (float*)d_ws;        // q|k|v : 3*QSZ floats
    float* y   = qkv + 3 * QSZ;       // [B,T,C]: QSZ floats   (total ~50 MB)

    // QKV GEMM: M=4096, N=2304 -> grid (36, 64)
    qkv_gemm_kernel<<<dim3(36, 64), 256, 0, stream>>>(x, W_attn, b_attn, qkv);

    // Attention: B*H*T waves = 49152, 4 waves/block -> 12288 blocks
    attn_kernel<<<dim3((BATCH * N_HEAD * SEQ) / 4), 256, 0, stream>>>(qkv, y);

    // Proj GEMM: M=4096, N=768 -> grid (12, 64)
    proj_gemm_kernel<<<dim3(12, 64), 256, 0, stream>>>(y, W_proj, b_proj, out);
}

// Round 2
// 472.305 us; speedup vs baseline: 8.4606x; 8.4606x over previous
//
#include <hip/hip_runtime.h>
#include <math.h>

#define N_EMBD 768
#define N_HEAD 12
#define HEAD_DIM 64
#define SEQ 2048
#define BATCH 2

typedef __attribute__((ext_vector_type(8))) short v8s;   // 8 bf16 (4 VGPRs)
typedef __attribute__((ext_vector_type(4))) float v4f;   // 4 fp32

// float -> bf16 bits, round-to-nearest-even
__device__ __forceinline__ unsigned short f2bf(float f) {
    union { float f; unsigned int u; } x; x.f = f;
    unsigned int u = x.u + 0x7fffu + ((x.u >> 16) & 1u);
    return (unsigned short)(u >> 16);
}

// Q pre-scale: 1/sqrt(64) * log2(e)  (softmax then uses exp2)
#define QSCALE 0.1803368801111396f

// ---------------------------------------------------------------------------
// Kernel 1: QKV projection (fp32 compute).  x[4096,768] @ W[768,2304] + b.
// Epilogue emits bf16: q -> [b,h,t,d] (pre-scaled by QSCALE), k -> [b,h,t,d],
// v -> [b,h,d,t] (TRANSPOSED so attention's V B-fragments are contiguous).
// ---------------------------------------------------------------------------
__global__ __launch_bounds__(256) void qkv_gemm_kernel(
    const float* __restrict__ x,     // [4096, 768]
    const float* __restrict__ W,     // [768, 2304]
    const float* __restrict__ bias,  // [2304]
    unsigned short* __restrict__ qg, // bf16 [24][2048][64]
    unsigned short* __restrict__ kg, // bf16 [24][2048][64]
    unsigned short* __restrict__ vg) // bf16 [24][64][2048]
{
    const int K = N_EMBD;
    const int N = 3 * N_EMBD;
    __shared__ float xs[16][65];
    __shared__ float ws[16][68];

    const int bm = blockIdx.y * 64;
    const int bn = blockIdx.x * 64;
    const int tid = threadIdx.x;
    const int tx = tid & 15;
    const int ty = tid >> 4;

    float acc[4][4];
#pragma unroll
    for (int i = 0; i < 4; i++)
#pragma unroll
        for (int j = 0; j < 4; j++) acc[i][j] = 0.f;

    for (int k0 = 0; k0 < K; k0 += 16) {
        {
            const int m = tid >> 2;
            const int kk = (tid & 3) << 2;
            const float4 xv = *(const float4*)(x + (size_t)(bm + m) * K + k0 + kk);
            xs[kk + 0][m] = xv.x; xs[kk + 1][m] = xv.y;
            xs[kk + 2][m] = xv.z; xs[kk + 3][m] = xv.w;
        }
        {
            const int kk = tid >> 4;
            const int n = (tid & 15) << 2;
            const float4 wv = *(const float4*)(W + (size_t)(k0 + kk) * N + bn + n);
            ws[kk][n + 0] = wv.x; ws[kk][n + 1] = wv.y;
            ws[kk][n + 2] = wv.z; ws[kk][n + 3] = wv.w;
        }
        __syncthreads();
#pragma unroll
        for (int kk = 0; kk < 16; kk++) {
            float a[4], b[4];
#pragma unroll
            for (int i = 0; i < 4; i++) a[i] = xs[kk][ty * 4 + i];
#pragma unroll
            for (int j = 0; j < 4; j++) b[j] = ws[kk][tx * 4 + j];
#pragma unroll
            for (int i = 0; i < 4; i++)
#pragma unroll
                for (int j = 0; j < 4; j++) acc[i][j] += a[i] * b[j];
        }
        __syncthreads();
    }

    const int which = bn / N_EMBD;   // 0=q 1=k 2=v
    const int rem = bn - which * N_EMBD;
    const int h = rem >> 6;

    if (which == 2) {
        // v transposed: [bh][d][t]; pack 4 consecutive t per store
        const int m0 = bm + ty * 4;
        const int b = m0 >> 11;
        const int t0 = m0 & (SEQ - 1);
        const size_t bh = (size_t)(b * N_HEAD + h);
#pragma unroll
        for (int j = 0; j < 4; j++) {
            const int d = tx * 4 + j;
            const float bv = bias[bn + d];
            ushort4 o;
            o.x = f2bf(acc[0][j] + bv);
            o.y = f2bf(acc[1][j] + bv);
            o.z = f2bf(acc[2][j] + bv);
            o.w = f2bf(acc[3][j] + bv);
            *(ushort4*)(vg + (bh * 64 + d) * SEQ + t0) = o;
        }
    } else {
        unsigned short* dst = (which == 0) ? qg : kg;
        const float sc = (which == 0) ? QSCALE : 1.0f;
#pragma unroll
        for (int i = 0; i < 4; i++) {
            const int m = bm + ty * 4 + i;
            const int b = m >> 11;
            const int t = m & (SEQ - 1);
            const size_t base = (((size_t)(b * N_HEAD + h)) * SEQ + t) * 64;
            ushort4 o;
            o.x = f2bf((acc[i][0] + bias[bn + tx * 4 + 0]) * sc);
            o.y = f2bf((acc[i][1] + bias[bn + tx * 4 + 1]) * sc);
            o.z = f2bf((acc[i][2] + bias[bn + tx * 4 + 2]) * sc);
            o.w = f2bf((acc[i][3] + bias[bn + tx * 4 + 3]) * sc);
            *(ushort4*)(dst + base + tx * 4) = o;
        }
    }
}

// ---------------------------------------------------------------------------
// Kernel 2: causal flash attention, bf16 MFMA (16x16x32), fp32 accumulate.
// Block = (b,h, 64-query tile); 4 waves, each owns a 16-row Q stripe.
// Verified gfx950 layouts: A[m=lane&15][k=quad*8+j], B[n=lane&15][k=quad*8+j],
// C/D[row=quad*4+reg][col=lane&15].
// ---------------------------------------------------------------------------
#define PITCH 72  // bf16 elements per LDS row: 144B = 16B-aligned, 2-way-free banks

__global__ __launch_bounds__(256) void attn_kernel(
    const unsigned short* __restrict__ qg,  // bf16 [24][2048][64], pre-scaled
    const unsigned short* __restrict__ kg,  // bf16 [24][2048][64]
    const unsigned short* __restrict__ vg,  // bf16 [24][64][2048]
    float* __restrict__ y)                  // fp32 [B,T,C]
{
    __shared__ unsigned short qs[64 * PITCH];
    __shared__ unsigned short ks[64 * PITCH];
    __shared__ unsigned short vs[64 * PITCH];
    __shared__ unsigned short ps[4][16 * PITCH];

    const int tid  = threadIdx.x;
    const int w    = tid >> 6;
    const int lane = tid & 63;
    const int quad = lane >> 4;
    const int c    = lane & 15;

    const int qt = 31 - (int)blockIdx.x;       // long blocks first
    const int bh = (int)blockIdx.y;            // b*N_HEAD + h
    const int qbase = qt * 64;

    const unsigned short* qrow = qg + (size_t)bh * SEQ * 64;
    const unsigned short* krow = kg + (size_t)bh * SEQ * 64;
    const unsigned short* vrow = vg + (size_t)bh * 64 * SEQ;

    // ---- stage Q tile (64 rows x 64 d) ----
#pragma unroll
    for (int p = 0; p < 2; p++) {
        const int idx = tid + p * 256;
        const int row = idx >> 3, ch = idx & 7;
        uint4 u = *(const uint4*)(qrow + ((size_t)(qbase + row)) * 64 + ch * 8);
        *(uint4*)&qs[row * PITCH + ch * 8] = u;
    }
    __syncthreads();

    // Q A-fragments are invariant across k-tiles: hoist.
    v8s aq0 = *(const v8s*)&qs[(w * 16 + c) * PITCH +  0 + quad * 8];
    v8s aq1 = *(const v8s*)&qs[(w * 16 + c) * PITCH + 32 + quad * 8];

    v4f oacc[4];
#pragma unroll
    for (int d = 0; d < 4; d++) oacc[d] = (v4f){0.f, 0.f, 0.f, 0.f};
    float m_r[4] = {-INFINITY, -INFINITY, -INFINITY, -INFINITY};
    float l_r[4] = {0.f, 0.f, 0.f, 0.f};

    const int nk = qt + 1;
    for (int kt = 0; kt < nk; kt++) {
        const int key0 = kt * 64;
        __syncthreads();  // previous tile's ks/vs reads complete
        // ---- stage K tile [key][d] and V tile [d][key] ----
#pragma unroll
        for (int p = 0; p < 2; p++) {
            const int idx = tid + p * 256;
            const int row = idx >> 3, ch = idx & 7;
            uint4 ku = *(const uint4*)(krow + ((size_t)(key0 + row)) * 64 + ch * 8);
            *(uint4*)&ks[row * PITCH + ch * 8] = ku;
            uint4 vu = *(const uint4*)(vrow + (size_t)row * SEQ + key0 + ch * 8);
            *(uint4*)&vs[row * PITCH + ch * 8] = vu;
        }
        __syncthreads();

        // ---- S = Q K^T  (16x64 stripe per wave) ----
        v4f sacc[4];
#pragma unroll
        for (int n = 0; n < 4; n++) {
            v4f s = (v4f){0.f, 0.f, 0.f, 0.f};
            v8s b0 = *(const v8s*)&ks[(n * 16 + c) * PITCH +  0 + quad * 8];
            s = __builtin_amdgcn_mfma_f32_16x16x32_bf16(aq0, b0, s, 0, 0, 0);
            v8s b1 = *(const v8s*)&ks[(n * 16 + c) * PITCH + 32 + quad * 8];
            s = __builtin_amdgcn_mfma_f32_16x16x32_bf16(aq1, b1, s, 0, 0, 0);
            sacc[n] = s;
        }

        // ---- causal mask (only diagonal tile has masked entries) ----
        if (kt == nk - 1) {
            const int tq0 = qbase + w * 16 + quad * 4;
#pragma unroll
            for (int n = 0; n < 4; n++) {
                const int key = key0 + n * 16 + c;
#pragma unroll
                for (int r = 0; r < 4; r++)
                    if (key > tq0 + r) sacc[n][r] = -1e30f;
            }
        }

        // ---- online softmax on the stripe ----
        float mx[4];
#pragma unroll
        for (int r = 0; r < 4; r++)
            mx[r] = fmaxf(fmaxf(sacc[0][r], sacc[1][r]), fmaxf(sacc[2][r], sacc[3][r]));
#pragma unroll
        for (int msk = 1; msk <= 8; msk <<= 1)
#pragma unroll
            for (int r = 0; r < 4; r++)
                mx[r] = fmaxf(mx[r], __shfl_xor(mx[r], msk, 64));

        float alpha[4];
#pragma unroll
        for (int r = 0; r < 4; r++) {
            const float mn = fmaxf(m_r[r], mx[r]);
            alpha[r] = exp2f(m_r[r] - mn);
            m_r[r] = mn;
        }

        float rs[4] = {0.f, 0.f, 0.f, 0.f};
#pragma unroll
        for (int n = 0; n < 4; n++)
#pragma unroll
            for (int r = 0; r < 4; r++) {
                const float p = exp2f(sacc[n][r] - m_r[r]);
                sacc[n][r] = p;
                rs[r] += p;
            }
#pragma unroll
        for (int msk = 1; msk <= 8; msk <<= 1)
#pragma unroll
            for (int r = 0; r < 4; r++)
                rs[r] += __shfl_xor(rs[r], msk, 64);
#pragma unroll
        for (int r = 0; r < 4; r++) l_r[r] = l_r[r] * alpha[r] + rs[r];

        // ---- P (C-layout) -> LDS (A-layout source), rescale O ----
#pragma unroll
        for (int n = 0; n < 4; n++)
#pragma unroll
            for (int r = 0; r < 4; r++)
                ps[w][(quad * 4 + r) * PITCH + n * 16 + c] = f2bf(sacc[n][r]);
#pragma unroll
        for (int d = 0; d < 4; d++)
#pragma unroll
            for (int r = 0; r < 4; r++) oacc[d][r] *= alpha[r];

        // ---- O += P V ----
        v8s ap0 = *(const v8s*)&ps[w][c * PITCH +  0 + quad * 8];
        v8s ap1 = *(const v8s*)&ps[w][c * PITCH + 32 + quad * 8];
#pragma unroll
        for (int d = 0; d < 4; d++) {
            v8s bv0 = *(const v8s*)&vs[(d * 16 + c) * PITCH +  0 + quad * 8];
            oacc[d] = __builtin_amdgcn_mfma_f32_16x16x32_bf16(ap0, bv0, oacc[d], 0, 0, 0);
            v8s bv1 = *(const v8s*)&vs[(d * 16 + c) * PITCH + 32 + quad * 8];
            oacc[d] = __builtin_amdgcn_mfma_f32_16x16x32_bf16(ap1, bv1, oacc[d], 0, 0, 0);
        }
    }

    // ---- epilogue: O / l -> y fp32 [B,T,C] ----
    const int b = bh / N_HEAD;
    const int h = bh - b * N_HEAD;
#pragma unroll
    for (int r = 0; r < 4; r++) {
        const float linv = 1.0f / l_r[r];
        const int tq = qbase + w * 16 + quad * 4 + r;
        float* yr = y + ((size_t)(b * SEQ + tq)) * N_EMBD + h * 64;
#pragma unroll
        for (int d = 0; d < 4; d++)
            yr[d * 16 + c] = oacc[d][r] * linv;
    }
}

// ---------------------------------------------------------------------------
// Kernel 3: output projection (fp32).  y[4096,768] @ W_proj[768,768] + b.
// ---------------------------------------------------------------------------
__global__ __launch_bounds__(256) void proj_gemm_kernel(
    const float* __restrict__ y,
    const float* __restrict__ W,
    const float* __restrict__ bias,
    float* __restrict__ out)
{
    const int K = N_EMBD;
    const int N = N_EMBD;
    __shared__ float xs[16][65];
    __shared__ float ws[16][68];

    const int bm = blockIdx.y * 64;
    const int bn = blockIdx.x * 64;
    const int tid = threadIdx.x;
    const int tx = tid & 15;
    const int ty = tid >> 4;

    float acc[4][4];
#pragma unroll
    for (int i = 0; i < 4; i++)
#pragma unroll
        for (int j = 0; j < 4; j++) acc[i][j] = 0.f;

    for (int k0 = 0; k0 < K; k0 += 16) {
        {
            const int m = tid >> 2;
            const int kk = (tid & 3) << 2;
            const float4 xv = *(const float4*)(y + (size_t)(bm + m) * K + k0 + kk);
            xs[kk + 0][m] = xv.x; xs[kk + 1][m] = xv.y;
            xs[kk + 2][m] = xv.z; xs[kk + 3][m] = xv.w;
        }
        {
            const int kk = tid >> 4;
            const int n = (tid & 15) << 2;
            const float4 wv = *(const float4*)(W + (size_t)(k0 + kk) * N + bn + n);
            ws[kk][n + 0] = wv.x; ws[kk][n + 1] = wv.y;
            ws[kk][n + 2] = wv.z; ws[kk][n + 3] = wv.w;
        }
        __syncthreads();
#pragma unroll
        for (int kk = 0; kk < 16; kk++) {
            float a[4], b[4];
#pragma unroll
            for (int i = 0; i < 4; i++) a[i] = xs[kk][ty * 4 + i];
#pragma unroll
            for (int j = 0; j < 4; j++) b[j] = ws[kk][tx * 4 + j];
#pragma unroll
            for (int i = 0; i < 4; i++)
#pragma unroll
                for (int j = 0; j < 4; j++) acc[i][j] += a[i] * b[j];
        }
        __syncthreads();
    }

#pragma unroll
    for (int i = 0; i < 4; i++) {
        const int m = bm + ty * 4 + i;
#pragma unroll
        for (int j = 0; j < 4; j++) {
            const int n = bn + tx * 4 + j;
            out[(size_t)m * N + n] = acc[i][j] + bias[n];
        }
    }
}

// ---------------------------------------------------------------------------
extern "C" void kernel_launch(void* const* d_in, const int* in_sizes, int n_in,
                              void* d_out, int out_size, void* d_ws, size_t ws_size,
                              hipStream_t stream) {
    const float* x      = (const float*)d_in[0];
    const float* W_attn = (const float*)d_in[1];
    const float* b_attn = (const float*)d_in[2];
    const float* W_proj = (const float*)d_in[3];
    const float* b_proj = (const float*)d_in[4];
    float* out = (float*)d_out;

    const size_t QSZ = (size_t)BATCH * N_HEAD * SEQ * HEAD_DIM;  // 3,145,728
    unsigned short* qg = (unsigned short*)d_ws;
    unsigned short* kg = qg + QSZ;
    unsigned short* vg = kg + QSZ;
    float* y = (float*)(vg + QSZ);   // offset 18.9 MB, 16B-aligned

    qkv_gemm_kernel<<<dim3(36, 64), 256, 0, stream>>>(x, W_attn, b_attn, qg, kg, vg);
    attn_kernel<<<dim3(32, BATCH * N_HEAD), 256, 0, stream>>>(qg, kg, vg, y);
    proj_gemm_kernel<<<dim3(12, 64), 256, 0, stream>>>(y, W_proj, b_proj, out);
}

// Round 3
// 246.237 us; speedup vs baseline: 16.2283x; 1.9181x over previous
//
#include <hip/hip_runtime.h>
#include <math.h>

#define N_EMBD 768
#define N_HEAD 12
#define HEAD_DIM 64
#define SEQ 2048
#define BATCH 2

typedef __attribute__((ext_vector_type(8))) short v8s;   // 8 bf16 (4 VGPRs)
typedef __attribute__((ext_vector_type(4))) float v4f;   // 4 fp32

__device__ __forceinline__ unsigned short f2bf(float f) {
    union { float f; unsigned int u; } x; x.f = f;
    unsigned int u = x.u + 0x7fffu + ((x.u >> 16) & 1u);
    return (unsigned short)(u >> 16);
}

// async 16B global->LDS (lane i lands at ldsbase + i*16; lds ptrs must be
// computed in exactly lane order)
__device__ __forceinline__ void gload_lds16(const unsigned short* g, unsigned short* l) {
    __builtin_amdgcn_global_load_lds(
        (const __attribute__((address_space(1))) void*)g,
        (__attribute__((address_space(3))) void*)l, 16, 0, 0);
}

// Q pre-scale: 1/sqrt(64) * log2(e)
#define QSCALE 0.1803368801111396f

// ---------------------------------------------------------------------------
// cast x fp32 -> bf16 (8 elems/thread)
// ---------------------------------------------------------------------------
__global__ __launch_bounds__(256) void cast_x_kernel(
    const float* __restrict__ in, unsigned short* __restrict__ out)
{
    const int i = (blockIdx.x * 256 + threadIdx.x) * 8;
    const float4 a = *(const float4*)(in + i);
    const float4 b = *(const float4*)(in + i + 4);
    ushort4 s0, s1;
    s0.x = f2bf(a.x); s0.y = f2bf(a.y); s0.z = f2bf(a.z); s0.w = f2bf(a.w);
    s1.x = f2bf(b.x); s1.y = f2bf(b.y); s1.z = f2bf(b.z); s1.w = f2bf(b.w);
    *(ushort4*)(out + i) = s0;
    *(ushort4*)(out + i + 4) = s1;
}

// ---------------------------------------------------------------------------
// transpose + cast: in fp32 [R][C] -> out bf16 [C][R].  32x32 LDS tile.
// ---------------------------------------------------------------------------
__global__ __launch_bounds__(256) void transpose_cast_kernel(
    const float* __restrict__ in, unsigned short* __restrict__ out, int R, int C)
{
    __shared__ float t[32][33];
    const int bx = blockIdx.x * 32;  // col base
    const int by = blockIdx.y * 32;  // row base
    const int tx = threadIdx.x & 31, ty = threadIdx.x >> 5;
#pragma unroll
    for (int i = 0; i < 32; i += 8)
        t[ty + i][tx] = in[(size_t)(by + ty + i) * C + bx + tx];
    __syncthreads();
#pragma unroll
    for (int i = 0; i < 32; i += 8)
        out[(size_t)(bx + ty + i) * R + by + tx] = f2bf(t[tx][ty + i]);
}

// ---------------------------------------------------------------------------
// Kernel 1: QKV GEMM, bf16 MFMA (m97 structure).
// C[4096,2304] = A[4096,768] @ Bt[2304,768]^T ; epilogue scatters q/k/v.
// 128x128 tile, 4 waves (2x2), each 64x64 = 4x4 fragments. BK=32.
// ---------------------------------------------------------------------------
__global__ __launch_bounds__(256) void qkv_gemm_mfma(
    const unsigned short* __restrict__ A,    // bf16 [4096][768]
    const unsigned short* __restrict__ Bt,   // bf16 [2304][768]
    const float* __restrict__ bias,          // fp32 [2304]
    unsigned short* __restrict__ qg,         // bf16 [24][2048][64] (pre-scaled)
    unsigned short* __restrict__ kg,         // bf16 [24][2048][64]
    unsigned short* __restrict__ vg)         // bf16 [24][64][2048]
{
    __shared__ unsigned short as[128 * 32];
    __shared__ unsigned short bs[128 * 32];
    const int K = 768;
    const int tid = threadIdx.x;
    const int lane = tid & 63;
    const int w = tid >> 6;
    const int wm = w >> 1, wn = w & 1;
    const int quad = lane >> 4, c = lane & 15;
    const int bm = blockIdx.y * 128;
    const int bn = blockIdx.x * 128;

    v4f acc[4][4];
#pragma unroll
    for (int i = 0; i < 4; i++)
#pragma unroll
        for (int j = 0; j < 4; j++) acc[i][j] = (v4f){0.f, 0.f, 0.f, 0.f};

    for (int k0 = 0; k0 < K; k0 += 32) {
        __syncthreads();
#pragma unroll
        for (int p = 0; p < 2; p++) {
            const int idx = p * 256 + tid;
            const int row = idx >> 2;
            const int off = (idx & 3) * 8;
            gload_lds16(A  + (size_t)(bm + row) * K + k0 + off, &as[idx * 8]);
            gload_lds16(Bt + (size_t)(bn + row) * K + k0 + off, &bs[idx * 8]);
        }
        __syncthreads();

        v8s af[4], bf[4];
#pragma unroll
        for (int fm = 0; fm < 4; fm++)
            af[fm] = *(const v8s*)&as[(wm * 64 + fm * 16 + c) * 32 + quad * 8];
#pragma unroll
        for (int fn = 0; fn < 4; fn++)
            bf[fn] = *(const v8s*)&bs[(wn * 64 + fn * 16 + c) * 32 + quad * 8];
#pragma unroll
        for (int fm = 0; fm < 4; fm++)
#pragma unroll
            for (int fn = 0; fn < 4; fn++)
                acc[fm][fn] = __builtin_amdgcn_mfma_f32_16x16x32_bf16(af[fm], bf[fn], acc[fm][fn], 0, 0, 0);
    }

    // epilogue: n-tile lies wholly inside one of q/k/v (768 = 6*128)
    const int which = bn / N_EMBD;
    const int rem_base = bn - which * N_EMBD;
#pragma unroll
    for (int fm = 0; fm < 4; fm++) {
        const int m0 = bm + wm * 64 + fm * 16 + quad * 4;   // 4 consecutive rows
        const int b = m0 >> 11;
        const int t0 = m0 & (SEQ - 1);
#pragma unroll
        for (int fn = 0; fn < 4; fn++) {
            const int rem = rem_base + wn * 64 + fn * 16 + c;
            const int h = rem >> 6, d = rem & 63;
            const float bv = bias[bn + wn * 64 + fn * 16 + c];
            const size_t bh = (size_t)(b * N_HEAD + h);
            if (which == 2) {
                ushort4 o;
                o.x = f2bf(acc[fm][fn][0] + bv);
                o.y = f2bf(acc[fm][fn][1] + bv);
                o.z = f2bf(acc[fm][fn][2] + bv);
                o.w = f2bf(acc[fm][fn][3] + bv);
                *(ushort4*)(vg + (bh * 64 + d) * SEQ + t0) = o;
            } else {
                unsigned short* dst = (which == 0) ? qg : kg;
                const float sc = (which == 0) ? QSCALE : 1.0f;
#pragma unroll
                for (int r = 0; r < 4; r++)
                    dst[(bh * SEQ + t0 + r) * 64 + d] = f2bf((acc[fm][fn][r] + bv) * sc);
            }
        }
    }
}

// ---------------------------------------------------------------------------
// Kernel 2: causal flash attention, bf16 MFMA (unchanged except bf16 y out).
// ---------------------------------------------------------------------------
#define PITCH 72

__global__ __launch_bounds__(256) void attn_kernel(
    const unsigned short* __restrict__ qg,
    const unsigned short* __restrict__ kg,
    const unsigned short* __restrict__ vg,
    unsigned short* __restrict__ y)   // bf16 [B,T,C]
{
    __shared__ unsigned short qs[64 * PITCH];
    __shared__ unsigned short ks[64 * PITCH];
    __shared__ unsigned short vs[64 * PITCH];
    __shared__ unsigned short ps[4][16 * PITCH];

    const int tid  = threadIdx.x;
    const int w    = tid >> 6;
    const int lane = tid & 63;
    const int quad = lane >> 4;
    const int c    = lane & 15;

    const int qt = 31 - (int)blockIdx.x;
    const int bh = (int)blockIdx.y;
    const int qbase = qt * 64;

    const unsigned short* qrow = qg + (size_t)bh * SEQ * 64;
    const unsigned short* krow = kg + (size_t)bh * SEQ * 64;
    const unsigned short* vrow = vg + (size_t)bh * 64 * SEQ;

#pragma unroll
    for (int p = 0; p < 2; p++) {
        const int idx = tid + p * 256;
        const int row = idx >> 3, ch = idx & 7;
        uint4 u = *(const uint4*)(qrow + ((size_t)(qbase + row)) * 64 + ch * 8);
        *(uint4*)&qs[row * PITCH + ch * 8] = u;
    }
    __syncthreads();

    v8s aq0 = *(const v8s*)&qs[(w * 16 + c) * PITCH +  0 + quad * 8];
    v8s aq1 = *(const v8s*)&qs[(w * 16 + c) * PITCH + 32 + quad * 8];

    v4f oacc[4];
#pragma unroll
    for (int d = 0; d < 4; d++) oacc[d] = (v4f){0.f, 0.f, 0.f, 0.f};
    float m_r[4] = {-INFINITY, -INFINITY, -INFINITY, -INFINITY};
    float l_r[4] = {0.f, 0.f, 0.f, 0.f};

    const int nk = qt + 1;
    for (int kt = 0; kt < nk; kt++) {
        const int key0 = kt * 64;
        __syncthreads();
#pragma unroll
        for (int p = 0; p < 2; p++) {
            const int idx = tid + p * 256;
            const int row = idx >> 3, ch = idx & 7;
            uint4 ku = *(const uint4*)(krow + ((size_t)(key0 + row)) * 64 + ch * 8);
            *(uint4*)&ks[row * PITCH + ch * 8] = ku;
            uint4 vu = *(const uint4*)(vrow + (size_t)row * SEQ + key0 + ch * 8);
            *(uint4*)&vs[row * PITCH + ch * 8] = vu;
        }
        __syncthreads();

        v4f sacc[4];
#pragma unroll
        for (int n = 0; n < 4; n++) {
            v4f s = (v4f){0.f, 0.f, 0.f, 0.f};
            v8s b0 = *(const v8s*)&ks[(n * 16 + c) * PITCH +  0 + quad * 8];
            s = __builtin_amdgcn_mfma_f32_16x16x32_bf16(aq0, b0, s, 0, 0, 0);
            v8s b1 = *(const v8s*)&ks[(n * 16 + c) * PITCH + 32 + quad * 8];
            s = __builtin_amdgcn_mfma_f32_16x16x32_bf16(aq1, b1, s, 0, 0, 0);
            sacc[n] = s;
        }

        if (kt == nk - 1) {
            const int tq0 = qbase + w * 16 + quad * 4;
#pragma unroll
            for (int n = 0; n < 4; n++) {
                const int key = key0 + n * 16 + c;
#pragma unroll
                for (int r = 0; r < 4; r++)
                    if (key > tq0 + r) sacc[n][r] = -1e30f;
            }
        }

        float mx[4];
#pragma unroll
        for (int r = 0; r < 4; r++)
            mx[r] = fmaxf(fmaxf(sacc[0][r], sacc[1][r]), fmaxf(sacc[2][r], sacc[3][r]));
#pragma unroll
        for (int msk = 1; msk <= 8; msk <<= 1)
#pragma unroll
            for (int r = 0; r < 4; r++)
                mx[r] = fmaxf(mx[r], __shfl_xor(mx[r], msk, 64));

        float alpha[4];
#pragma unroll
        for (int r = 0; r < 4; r++) {
            const float mn = fmaxf(m_r[r], mx[r]);
            alpha[r] = exp2f(m_r[r] - mn);
            m_r[r] = mn;
        }

        float rs[4] = {0.f, 0.f, 0.f, 0.f};
#pragma unroll
        for (int n = 0; n < 4; n++)
#pragma unroll
            for (int r = 0; r < 4; r++) {
                const float p = exp2f(sacc[n][r] - m_r[r]);
                sacc[n][r] = p;
                rs[r] += p;
            }
#pragma unroll
        for (int msk = 1; msk <= 8; msk <<= 1)
#pragma unroll
            for (int r = 0; r < 4; r++)
                rs[r] += __shfl_xor(rs[r], msk, 64);
#pragma unroll
        for (int r = 0; r < 4; r++) l_r[r] = l_r[r] * alpha[r] + rs[r];

#pragma unroll
        for (int n = 0; n < 4; n++)
#pragma unroll
            for (int r = 0; r < 4; r++)
                ps[w][(quad * 4 + r) * PITCH + n * 16 + c] = f2bf(sacc[n][r]);
#pragma unroll
        for (int d = 0; d < 4; d++)
#pragma unroll
            for (int r = 0; r < 4; r++) oacc[d][r] *= alpha[r];

        v8s ap0 = *(const v8s*)&ps[w][c * PITCH +  0 + quad * 8];
        v8s ap1 = *(const v8s*)&ps[w][c * PITCH + 32 + quad * 8];
#pragma unroll
        for (int d = 0; d < 4; d++) {
            v8s bv0 = *(const v8s*)&vs[(d * 16 + c) * PITCH +  0 + quad * 8];
            oacc[d] = __builtin_amdgcn_mfma_f32_16x16x32_bf16(ap0, bv0, oacc[d], 0, 0, 0);
            v8s bv1 = *(const v8s*)&vs[(d * 16 + c) * PITCH + 32 + quad * 8];
            oacc[d] = __builtin_amdgcn_mfma_f32_16x16x32_bf16(ap1, bv1, oacc[d], 0, 0, 0);
        }
    }

    const int b = bh / N_HEAD;
    const int h = bh - b * N_HEAD;
#pragma unroll
    for (int r = 0; r < 4; r++) {
        const float linv = 1.0f / l_r[r];
        const int tq = qbase + w * 16 + quad * 4 + r;
        unsigned short* yr = y + ((size_t)(b * SEQ + tq)) * N_EMBD + h * 64;
#pragma unroll
        for (int d = 0; d < 4; d++)
            yr[d * 16 + c] = f2bf(oacc[d][r] * linv);
    }
}

// ---------------------------------------------------------------------------
// Kernel 3: output projection, bf16 MFMA. out fp32 = y @ Wp^T + b.
// ---------------------------------------------------------------------------
__global__ __launch_bounds__(256) void proj_gemm_mfma(
    const unsigned short* __restrict__ A,    // bf16 y [4096][768]
    const unsigned short* __restrict__ Bt,   // bf16 Wp^T [768][768]
    const float* __restrict__ bias,          // [768]
    float* __restrict__ out)                 // fp32 [4096][768]
{
    __shared__ unsigned short as[128 * 32];
    __shared__ unsigned short bs[128 * 32];
    const int K = 768;
    const int tid = threadIdx.x;
    const int lane = tid & 63;
    const int w = tid >> 6;
    const int wm = w >> 1, wn = w & 1;
    const int quad = lane >> 4, c = lane & 15;
    const int bm = blockIdx.y * 128;
    const int bn = blockIdx.x * 128;

    v4f acc[4][4];
#pragma unroll
    for (int i = 0; i < 4; i++)
#pragma unroll
        for (int j = 0; j < 4; j++) acc[i][j] = (v4f){0.f, 0.f, 0.f, 0.f};

    for (int k0 = 0; k0 < K; k0 += 32) {
        __syncthreads();
#pragma unroll
        for (int p = 0; p < 2; p++) {
            const int idx = p * 256 + tid;
            const int row = idx >> 2;
            const int off = (idx & 3) * 8;
            gload_lds16(A  + (size_t)(bm + row) * K + k0 + off, &as[idx * 8]);
            gload_lds16(Bt + (size_t)(bn + row) * K + k0 + off, &bs[idx * 8]);
        }
        __syncthreads();

        v8s af[4], bf[4];
#pragma unroll
        for (int fm = 0; fm < 4; fm++)
            af[fm] = *(const v8s*)&as[(wm * 64 + fm * 16 + c) * 32 + quad * 8];
#pragma unroll
        for (int fn = 0; fn < 4; fn++)
            bf[fn] = *(const v8s*)&bs[(wn * 64 + fn * 16 + c) * 32 + quad * 8];
#pragma unroll
        for (int fm = 0; fm < 4; fm++)
#pragma unroll
            for (int fn = 0; fn < 4; fn++)
                acc[fm][fn] = __builtin_amdgcn_mfma_f32_16x16x32_bf16(af[fm], bf[fn], acc[fm][fn], 0, 0, 0);
    }

#pragma unroll
    for (int fm = 0; fm < 4; fm++) {
        const int m0 = bm + wm * 64 + fm * 16 + quad * 4;
#pragma unroll
        for (int fn = 0; fn < 4; fn++) {
            const int n = bn + wn * 64 + fn * 16 + c;
            const float bv = bias[n];
#pragma unroll
            for (int r = 0; r < 4; r++)
                out[(size_t)(m0 + r) * N_EMBD + n] = acc[fm][fn][r] + bv;
        }
    }
}

// ---------------------------------------------------------------------------
extern "C" void kernel_launch(void* const* d_in, const int* in_sizes, int n_in,
                              void* d_out, int out_size, void* d_ws, size_t ws_size,
                              hipStream_t stream) {
    const float* x      = (const float*)d_in[0];
    const float* W_attn = (const float*)d_in[1];
    const float* b_attn = (const float*)d_in[2];
    const float* W_proj = (const float*)d_in[3];
    const float* b_proj = (const float*)d_in[4];
    float* out = (float*)d_out;

    const size_t QSZ = (size_t)BATCH * N_HEAD * SEQ * HEAD_DIM;  // 3,145,728
    unsigned short* xb  = (unsigned short*)d_ws;                 // [4096][768]
    unsigned short* wta = xb + QSZ;                              // [2304][768]
    unsigned short* wtp = wta + (size_t)3 * N_EMBD * N_EMBD;     // [768][768]
    unsigned short* qg  = wtp + (size_t)N_EMBD * N_EMBD;
    unsigned short* kg  = qg + QSZ;
    unsigned short* vg  = kg + QSZ;
    unsigned short* yb  = vg + QSZ;                              // [4096][768]

    cast_x_kernel<<<dim3((int)(QSZ / (256 * 8))), 256, 0, stream>>>(x, xb);
    transpose_cast_kernel<<<dim3(72, 24), 256, 0, stream>>>(W_attn, wta, N_EMBD, 3 * N_EMBD);
    transpose_cast_kernel<<<dim3(24, 24), 256, 0, stream>>>(W_proj, wtp, N_EMBD, N_EMBD);

    qkv_gemm_mfma<<<dim3(18, 32), 256, 0, stream>>>(xb, wta, b_attn, qg, kg, vg);
    attn_kernel<<<dim3(32, BATCH * N_HEAD), 256, 0, stream>>>(qg, kg, vg, yb);
    proj_gemm_mfma<<<dim3(6, 32), 256, 0, stream>>>(yb, wtp, b_proj, out);
}

// Round 4
// 210.820 us; speedup vs baseline: 18.9546x; 1.1680x over previous
//
#include <hip/hip_runtime.h>
#include <math.h>

#define N_EMBD 768
#define N_HEAD 12
#define HEAD_DIM 64
#define SEQ 2048
#define BATCH 2

typedef __attribute__((ext_vector_type(8))) short v8s;   // 8 bf16 (4 VGPRs)
typedef __attribute__((ext_vector_type(4))) float v4f;   // 4 fp32

__device__ __forceinline__ unsigned short f2bf(float f) {
    union { float f; unsigned int u; } x; x.f = f;
    unsigned int u = x.u + 0x7fffu + ((x.u >> 16) & 1u);
    return (unsigned short)(u >> 16);
}
__device__ __forceinline__ float bf2f(unsigned short s) {
    union { unsigned int u; float f; } x; x.u = ((unsigned int)s) << 16;
    return x.f;
}

__device__ __forceinline__ void gload_lds16(const unsigned short* g, unsigned short* l) {
    __builtin_amdgcn_global_load_lds(
        (const __attribute__((address_space(1))) void*)g,
        (__attribute__((address_space(3))) void*)l, 16, 0, 0);
}

// Q pre-scale: 1/sqrt(64) * log2(e)
#define QSCALE 0.1803368801111396f

// ---------------------------------------------------------------------------
__global__ __launch_bounds__(256) void cast_x_kernel(
    const float* __restrict__ in, unsigned short* __restrict__ out)
{
    const int i = (blockIdx.x * 256 + threadIdx.x) * 8;
    const float4 a = *(const float4*)(in + i);
    const float4 b = *(const float4*)(in + i + 4);
    ushort4 s0, s1;
    s0.x = f2bf(a.x); s0.y = f2bf(a.y); s0.z = f2bf(a.z); s0.w = f2bf(a.w);
    s1.x = f2bf(b.x); s1.y = f2bf(b.y); s1.z = f2bf(b.z); s1.w = f2bf(b.w);
    *(ushort4*)(out + i) = s0;
    *(ushort4*)(out + i + 4) = s1;
}

// ---------------------------------------------------------------------------
__global__ __launch_bounds__(256) void transpose_cast_kernel(
    const float* __restrict__ in, unsigned short* __restrict__ out, int R, int C)
{
    __shared__ float t[32][33];
    const int bx = blockIdx.x * 32;
    const int by = blockIdx.y * 32;
    const int tx = threadIdx.x & 31, ty = threadIdx.x >> 5;
#pragma unroll
    for (int i = 0; i < 32; i += 8)
        t[ty + i][tx] = in[(size_t)(by + ty + i) * C + bx + tx];
    __syncthreads();
#pragma unroll
    for (int i = 0; i < 32; i += 8)
        out[(size_t)(bx + ty + i) * R + by + tx] = f2bf(t[tx][ty + i]);
}

// ---------------------------------------------------------------------------
// Kernel 1: QKV GEMM, bf16 MFMA (m97 structure), unchanged from round 3.
// ---------------------------------------------------------------------------
__global__ __launch_bounds__(256) void qkv_gemm_mfma(
    const unsigned short* __restrict__ A,
    const unsigned short* __restrict__ Bt,
    const float* __restrict__ bias,
    unsigned short* __restrict__ qg,
    unsigned short* __restrict__ kg,
    unsigned short* __restrict__ vg)
{
    __shared__ unsigned short as[128 * 32];
    __shared__ unsigned short bs[128 * 32];
    const int K = 768;
    const int tid = threadIdx.x;
    const int lane = tid & 63;
    const int w = tid >> 6;
    const int wm = w >> 1, wn = w & 1;
    const int quad = lane >> 4, c = lane & 15;
    const int bm = blockIdx.y * 128;
    const int bn = blockIdx.x * 128;

    v4f acc[4][4];
#pragma unroll
    for (int i = 0; i < 4; i++)
#pragma unroll
        for (int j = 0; j < 4; j++) acc[i][j] = (v4f){0.f, 0.f, 0.f, 0.f};

    for (int k0 = 0; k0 < K; k0 += 32) {
        __syncthreads();
#pragma unroll
        for (int p = 0; p < 2; p++) {
            const int idx = p * 256 + tid;
            const int row = idx >> 2;
            const int off = (idx & 3) * 8;
            gload_lds16(A  + (size_t)(bm + row) * K + k0 + off, &as[idx * 8]);
            gload_lds16(Bt + (size_t)(bn + row) * K + k0 + off, &bs[idx * 8]);
        }
        __syncthreads();

        v8s af[4], bf[4];
#pragma unroll
        for (int fm = 0; fm < 4; fm++)
            af[fm] = *(const v8s*)&as[(wm * 64 + fm * 16 + c) * 32 + quad * 8];
#pragma unroll
        for (int fn = 0; fn < 4; fn++)
            bf[fn] = *(const v8s*)&bs[(wn * 64 + fn * 16 + c) * 32 + quad * 8];
#pragma unroll
        for (int fm = 0; fm < 4; fm++)
#pragma unroll
            for (int fn = 0; fn < 4; fn++)
                acc[fm][fn] = __builtin_amdgcn_mfma_f32_16x16x32_bf16(af[fm], bf[fn], acc[fm][fn], 0, 0, 0);
    }

    const int which = bn / N_EMBD;
    const int rem_base = bn - which * N_EMBD;
#pragma unroll
    for (int fm = 0; fm < 4; fm++) {
        const int m0 = bm + wm * 64 + fm * 16 + quad * 4;
        const int b = m0 >> 11;
        const int t0 = m0 & (SEQ - 1);
#pragma unroll
        for (int fn = 0; fn < 4; fn++) {
            const int rem = rem_base + wn * 64 + fn * 16 + c;
            const int h = rem >> 6, d = rem & 63;
            const float bv = bias[bn + wn * 64 + fn * 16 + c];
            const size_t bh = (size_t)(b * N_HEAD + h);
            if (which == 2) {
                ushort4 o;
                o.x = f2bf(acc[fm][fn][0] + bv);
                o.y = f2bf(acc[fm][fn][1] + bv);
                o.z = f2bf(acc[fm][fn][2] + bv);
                o.w = f2bf(acc[fm][fn][3] + bv);
                *(ushort4*)(vg + (bh * 64 + d) * SEQ + t0) = o;
            } else {
                unsigned short* dst = (which == 0) ? qg : kg;
                const float sc = (which == 0) ? QSCALE : 1.0f;
#pragma unroll
                for (int r = 0; r < 4; r++)
                    dst[(bh * SEQ + t0 + r) * 64 + d] = f2bf((acc[fm][fn][r] + bv) * sc);
            }
        }
    }
}

// ---------------------------------------------------------------------------
// Kernel 2: causal flash attention with block-level split-K.
// chunk id c2 (ascending) -> (qt, kc): qt<8 -> 1 chunk, <16 -> 2, <24 -> 3,
// <32 -> 4.  Each chunk covers k-tiles [kc*8, min(kc*8+8, qt+1)).
// Writes unnormalized partials: O bf16 [pidx][64][64], m/l fp32 [pidx][64].
// LDS: ps aliases qs (Q frags hoisted to regs before first ps write).
// ---------------------------------------------------------------------------
#define PITCH 72

__global__ __launch_bounds__(256) void attn_kernel(
    const unsigned short* __restrict__ qg,
    const unsigned short* __restrict__ kg,
    const unsigned short* __restrict__ vg,
    unsigned short* __restrict__ pO,   // [1920*24? no: bh*80+c2][64][64] bf16
    float* __restrict__ pm,            // [bh*80+c2][64]
    float* __restrict__ pl)            // [bh*80+c2][64]
{
    __shared__ unsigned short qps[64 * PITCH];  // Q tile, then per-wave P
    __shared__ unsigned short ks[64 * PITCH];
    __shared__ unsigned short vs[64 * PITCH];

    const int tid  = threadIdx.x;
    const int w    = tid >> 6;
    const int lane = tid & 63;
    const int quad = lane >> 4;
    const int c    = lane & 15;

    const int c2 = 79 - (int)blockIdx.x;  // long chunks first
    int qt, kc;
    if (c2 < 8)       { qt = c2;                kc = 0; }
    else if (c2 < 24) { qt = 8 + ((c2 - 8) >> 1);  kc = (c2 - 8) & 1; }
    else if (c2 < 48) { qt = 16 + (c2 - 24) / 3;   kc = (c2 - 24) % 3; }
    else              { qt = 24 + ((c2 - 48) >> 2); kc = (c2 - 48) & 3; }
    const int bh = (int)blockIdx.y;
    const int qbase = qt * 64;

    const unsigned short* qrow = qg + (size_t)bh * SEQ * 64;
    const unsigned short* krow = kg + (size_t)bh * SEQ * 64;
    const unsigned short* vrow = vg + (size_t)bh * 64 * SEQ;

    // ---- stage Q tile ----
#pragma unroll
    for (int p = 0; p < 2; p++) {
        const int idx = tid + p * 256;
        const int row = idx >> 3, ch = idx & 7;
        uint4 u = *(const uint4*)(qrow + ((size_t)(qbase + row)) * 64 + ch * 8);
        *(uint4*)&qps[row * PITCH + ch * 8] = u;
    }
    __syncthreads();

    v8s aq0 = *(const v8s*)&qps[(w * 16 + c) * PITCH +  0 + quad * 8];
    v8s aq1 = *(const v8s*)&qps[(w * 16 + c) * PITCH + 32 + quad * 8];
    unsigned short* ps = &qps[w * 16 * PITCH];  // aliases Q tile (dead now)

    v4f oacc[4];
#pragma unroll
    for (int d = 0; d < 4; d++) oacc[d] = (v4f){0.f, 0.f, 0.f, 0.f};
    float m_r[4] = {-INFINITY, -INFINITY, -INFINITY, -INFINITY};
    float l_r[4] = {0.f, 0.f, 0.f, 0.f};

    const int kt0 = kc * 8;
    const int kt1 = min(kt0 + 8, qt + 1);
    for (int kt = kt0; kt < kt1; kt++) {
        const int key0 = kt * 64;
        __syncthreads();
#pragma unroll
        for (int p = 0; p < 2; p++) {
            const int idx = tid + p * 256;
            const int row = idx >> 3, ch = idx & 7;
            uint4 ku = *(const uint4*)(krow + ((size_t)(key0 + row)) * 64 + ch * 8);
            *(uint4*)&ks[row * PITCH + ch * 8] = ku;
            uint4 vu = *(const uint4*)(vrow + (size_t)row * SEQ + key0 + ch * 8);
            *(uint4*)&vs[row * PITCH + ch * 8] = vu;
        }
        __syncthreads();

        v4f sacc[4];
#pragma unroll
        for (int n = 0; n < 4; n++) {
            v4f s = (v4f){0.f, 0.f, 0.f, 0.f};
            v8s b0 = *(const v8s*)&ks[(n * 16 + c) * PITCH +  0 + quad * 8];
            s = __builtin_amdgcn_mfma_f32_16x16x32_bf16(aq0, b0, s, 0, 0, 0);
            v8s b1 = *(const v8s*)&ks[(n * 16 + c) * PITCH + 32 + quad * 8];
            s = __builtin_amdgcn_mfma_f32_16x16x32_bf16(aq1, b1, s, 0, 0, 0);
            sacc[n] = s;
        }

        if (kt == qt) {  // diagonal tile
            const int tq0 = qbase + w * 16 + quad * 4;
#pragma unroll
            for (int n = 0; n < 4; n++) {
                const int key = key0 + n * 16 + c;
#pragma unroll
                for (int r = 0; r < 4; r++)
                    if (key > tq0 + r) sacc[n][r] = -1e30f;
            }
        }

        float mx[4];
#pragma unroll
        for (int r = 0; r < 4; r++)
            mx[r] = fmaxf(fmaxf(sacc[0][r], sacc[1][r]), fmaxf(sacc[2][r], sacc[3][r]));
#pragma unroll
        for (int msk = 1; msk <= 8; msk <<= 1)
#pragma unroll
            for (int r = 0; r < 4; r++)
                mx[r] = fmaxf(mx[r], __shfl_xor(mx[r], msk, 64));

        float alpha[4];
#pragma unroll
        for (int r = 0; r < 4; r++) {
            const float mn = fmaxf(m_r[r], mx[r]);
            alpha[r] = exp2f(m_r[r] - mn);
            m_r[r] = mn;
        }

        float rs[4] = {0.f, 0.f, 0.f, 0.f};
#pragma unroll
        for (int n = 0; n < 4; n++)
#pragma unroll
            for (int r = 0; r < 4; r++) {
                const float p = exp2f(sacc[n][r] - m_r[r]);
                sacc[n][r] = p;
                rs[r] += p;
            }
#pragma unroll
        for (int msk = 1; msk <= 8; msk <<= 1)
#pragma unroll
            for (int r = 0; r < 4; r++)
                rs[r] += __shfl_xor(rs[r], msk, 64);
#pragma unroll
        for (int r = 0; r < 4; r++) l_r[r] = l_r[r] * alpha[r] + rs[r];

#pragma unroll
        for (int n = 0; n < 4; n++)
#pragma unroll
            for (int r = 0; r < 4; r++)
                ps[(quad * 4 + r) * PITCH + n * 16 + c] = f2bf(sacc[n][r]);
#pragma unroll
        for (int d = 0; d < 4; d++)
#pragma unroll
            for (int r = 0; r < 4; r++) oacc[d][r] *= alpha[r];

        v8s ap0 = *(const v8s*)&ps[c * PITCH +  0 + quad * 8];
        v8s ap1 = *(const v8s*)&ps[c * PITCH + 32 + quad * 8];
#pragma unroll
        for (int d = 0; d < 4; d++) {
            v8s bv0 = *(const v8s*)&vs[(d * 16 + c) * PITCH +  0 + quad * 8];
            oacc[d] = __builtin_amdgcn_mfma_f32_16x16x32_bf16(ap0, bv0, oacc[d], 0, 0, 0);
            v8s bv1 = *(const v8s*)&vs[(d * 16 + c) * PITCH + 32 + quad * 8];
            oacc[d] = __builtin_amdgcn_mfma_f32_16x16x32_bf16(ap1, bv1, oacc[d], 0, 0, 0);
        }
    }

    // ---- write unnormalized partials ----
    const size_t pidx = (size_t)bh * 80 + c2;
    unsigned short* po = pO + pidx * 4096;
#pragma unroll
    for (int r = 0; r < 4; r++) {
        const int row = w * 16 + quad * 4 + r;
#pragma unroll
        for (int d = 0; d < 4; d++)
            po[row * 64 + d * 16 + c] = f2bf(oacc[d][r]);
        if (c == 0) {
            pm[pidx * 64 + row] = m_r[r];
            pl[pidx * 64 + row] = l_r[r];
        }
    }
}

// ---------------------------------------------------------------------------
// Kernel 2b: combine partials -> y bf16 [B,T,C].
// grid (32 qt, 24 bh), 256 thr: row = tid>>2, 16 cols per thread.
// ---------------------------------------------------------------------------
__global__ __launch_bounds__(256) void combine_kernel(
    const unsigned short* __restrict__ pO,
    const float* __restrict__ pm,
    const float* __restrict__ pl,
    unsigned short* __restrict__ y)
{
    const int qt = (int)blockIdx.x;
    const int bh = (int)blockIdx.y;
    int base, nc;
    if (qt < 8)       { base = qt;                 nc = 1; }
    else if (qt < 16) { base = 8 + 2 * (qt - 8);   nc = 2; }
    else if (qt < 24) { base = 24 + 3 * (qt - 16); nc = 3; }
    else              { base = 48 + 4 * (qt - 24); nc = 4; }

    const int row = threadIdx.x >> 2;
    const int colg = (threadIdx.x & 3) * 16;

    float mi[4], li[4];
    float M = -INFINITY;
    for (int i = 0; i < nc; i++) {
        const size_t pidx = (size_t)bh * 80 + base + i;
        mi[i] = pm[pidx * 64 + row];
        li[i] = pl[pidx * 64 + row];
        M = fmaxf(M, mi[i]);
    }
    float denom = 0.f;
    float wgt[4];
    for (int i = 0; i < nc; i++) {
        wgt[i] = exp2f(mi[i] - M);
        denom += wgt[i] * li[i];
    }
    const float inv = 1.0f / denom;

    float acc[16];
#pragma unroll
    for (int j = 0; j < 16; j++) acc[j] = 0.f;
    for (int i = 0; i < nc; i++) {
        const unsigned short* po = pO + ((size_t)bh * 80 + base + i) * 4096 + row * 64 + colg;
        ushort4 u0 = *(const ushort4*)(po + 0);
        ushort4 u1 = *(const ushort4*)(po + 4);
        ushort4 u2 = *(const ushort4*)(po + 8);
        ushort4 u3 = *(const ushort4*)(po + 12);
        const float wv = wgt[i];
        acc[0]  += wv * bf2f(u0.x); acc[1]  += wv * bf2f(u0.y);
        acc[2]  += wv * bf2f(u0.z); acc[3]  += wv * bf2f(u0.w);
        acc[4]  += wv * bf2f(u1.x); acc[5]  += wv * bf2f(u1.y);
        acc[6]  += wv * bf2f(u1.z); acc[7]  += wv * bf2f(u1.w);
        acc[8]  += wv * bf2f(u2.x); acc[9]  += wv * bf2f(u2.y);
        acc[10] += wv * bf2f(u2.z); acc[11] += wv * bf2f(u2.w);
        acc[12] += wv * bf2f(u3.x); acc[13] += wv * bf2f(u3.y);
        acc[14] += wv * bf2f(u3.z); acc[15] += wv * bf2f(u3.w);
    }

    const int b = bh / N_HEAD;
    const int h = bh - b * N_HEAD;
    const int t = qt * 64 + row;
    unsigned short* yr = y + ((size_t)(b * SEQ + t)) * N_EMBD + h * 64 + colg;
    ushort4 o0, o1, o2, o3;
    o0.x = f2bf(acc[0] * inv);  o0.y = f2bf(acc[1] * inv);
    o0.z = f2bf(acc[2] * inv);  o0.w = f2bf(acc[3] * inv);
    o1.x = f2bf(acc[4] * inv);  o1.y = f2bf(acc[5] * inv);
    o1.z = f2bf(acc[6] * inv);  o1.w = f2bf(acc[7] * inv);
    o2.x = f2bf(acc[8] * inv);  o2.y = f2bf(acc[9] * inv);
    o2.z = f2bf(acc[10] * inv); o2.w = f2bf(acc[11] * inv);
    o3.x = f2bf(acc[12] * inv); o3.y = f2bf(acc[13] * inv);
    o3.z = f2bf(acc[14] * inv); o3.w = f2bf(acc[15] * inv);
    *(ushort4*)(yr + 0)  = o0;
    *(ushort4*)(yr + 4)  = o1;
    *(ushort4*)(yr + 8)  = o2;
    *(ushort4*)(yr + 12) = o3;
}

// ---------------------------------------------------------------------------
// Kernel 3: output projection, bf16 MFMA (unchanged).
// ---------------------------------------------------------------------------
__global__ __launch_bounds__(256) void proj_gemm_mfma(
    const unsigned short* __restrict__ A,
    const unsigned short* __restrict__ Bt,
    const float* __restrict__ bias,
    float* __restrict__ out)
{
    __shared__ unsigned short as[128 * 32];
    __shared__ unsigned short bs[128 * 32];
    const int K = 768;
    const int tid = threadIdx.x;
    const int lane = tid & 63;
    const int w = tid >> 6;
    const int wm = w >> 1, wn = w & 1;
    const int quad = lane >> 4, c = lane & 15;
    const int bm = blockIdx.y * 128;
    const int bn = blockIdx.x * 128;

    v4f acc[4][4];
#pragma unroll
    for (int i = 0; i < 4; i++)
#pragma unroll
        for (int j = 0; j < 4; j++) acc[i][j] = (v4f){0.f, 0.f, 0.f, 0.f};

    for (int k0 = 0; k0 < K; k0 += 32) {
        __syncthreads();
#pragma unroll
        for (int p = 0; p < 2; p++) {
            const int idx = p * 256 + tid;
            const int row = idx >> 2;
            const int off = (idx & 3) * 8;
            gload_lds16(A  + (size_t)(bm + row) * K + k0 + off, &as[idx * 8]);
            gload_lds16(Bt + (size_t)(bn + row) * K + k0 + off, &bs[idx * 8]);
        }
        __syncthreads();

        v8s af[4], bf[4];
#pragma unroll
        for (int fm = 0; fm < 4; fm++)
            af[fm] = *(const v8s*)&as[(wm * 64 + fm * 16 + c) * 32 + quad * 8];
#pragma unroll
        for (int fn = 0; fn < 4; fn++)
            bf[fn] = *(const v8s*)&bs[(wn * 64 + fn * 16 + c) * 32 + quad * 8];
#pragma unroll
        for (int fm = 0; fm < 4; fm++)
#pragma unroll
            for (int fn = 0; fn < 4; fn++)
                acc[fm][fn] = __builtin_amdgcn_mfma_f32_16x16x32_bf16(af[fm], bf[fn], acc[fm][fn], 0, 0, 0);
    }

#pragma unroll
    for (int fm = 0; fm < 4; fm++) {
        const int m0 = bm + wm * 64 + fm * 16 + quad * 4;
#pragma unroll
        for (int fn = 0; fn < 4; fn++) {
            const int n = bn + wn * 64 + fn * 16 + c;
            const float bv = bias[n];
#pragma unroll
            for (int r = 0; r < 4; r++)
                out[(size_t)(m0 + r) * N_EMBD + n] = acc[fm][fn][r] + bv;
        }
    }
}

// ---------------------------------------------------------------------------
extern "C" void kernel_launch(void* const* d_in, const int* in_sizes, int n_in,
                              void* d_out, int out_size, void* d_ws, size_t ws_size,
                              hipStream_t stream) {
    const float* x      = (const float*)d_in[0];
    const float* W_attn = (const float*)d_in[1];
    const float* b_attn = (const float*)d_in[2];
    const float* W_proj = (const float*)d_in[3];
    const float* b_proj = (const float*)d_in[4];
    float* out = (float*)d_out;

    const size_t QSZ = (size_t)BATCH * N_HEAD * SEQ * HEAD_DIM;  // 3,145,728

    // ws layout (bytes):
    //   [0 .. 15.73MB)  pO partials (1920*4096 bf16), ALIASED over xb+wta
    //                   (xb at 0, wta at +QSZ; both dead before attn writes)
    //   then pm, pl (fp32 1920*64 each), wtp, qg, kg, vg, yb.  Total ~43 MB.
    unsigned short* base = (unsigned short*)d_ws;
    unsigned short* xb  = base;                       // [4096][768]
    unsigned short* wta = base + QSZ;                 // [2304][768]
    unsigned short* pO  = base;                       // 1920*4096 ush (alias)
    float* pm = (float*)(base + (size_t)1920 * 4096); // 1920*64
    float* pl = pm + 1920 * 64;
    unsigned short* wtp = (unsigned short*)(pl + 1920 * 64);  // [768][768]
    unsigned short* qg  = wtp + (size_t)N_EMBD * N_EMBD;
    unsigned short* kg  = qg + QSZ;
    unsigned short* vg  = kg + QSZ;
    unsigned short* yb  = vg + QSZ;

    cast_x_kernel<<<dim3((int)(QSZ / (256 * 8))), 256, 0, stream>>>(x, xb);
    transpose_cast_kernel<<<dim3(72, 24), 256, 0, stream>>>(W_attn, wta, N_EMBD, 3 * N_EMBD);
    transpose_cast_kernel<<<dim3(24, 24), 256, 0, stream>>>(W_proj, wtp, N_EMBD, N_EMBD);

    qkv_gemm_mfma<<<dim3(18, 32), 256, 0, stream>>>(xb, wta, b_attn, qg, kg, vg);
    attn_kernel<<<dim3(80, BATCH * N_HEAD), 256, 0, stream>>>(qg, kg, vg, pO, pm, pl);
    combine_kernel<<<dim3(32, BATCH * N_HEAD), 256, 0, stream>>>(pO, pm, pl, yb);
    proj_gemm_mfma<<<dim3(6, 32), 256, 0, stream>>>(yb, wtp, b_proj, out);
}